// Round 8
// baseline (73.140 us; speedup 1.0000x reference)
//
#include <hip/hip_runtime.h>
#include <cmath>

#define MATSZ 262144  // 2048 * 128
// ws layout: qkv[m][2048][128] row-major, m: 0=Q (pre-scaled), 1=K, 2=V.
// Column e = h*8 + j (head-blocked), i.e. the natural reshape(B,S,H,dk).

#define CH  8448   // 64 keys * LDK floats per staged matrix
#define LDK 132    // padded row stride (128+4): b128 reads hit all 32 banks

// ---------------- k_qkvq: QKV projection + quantum closed form ---------------
// 16-row tiles, grid (128,3). thread = (col e, K-half); W row fragment in regs
// (issued first, L2-hot); x rows broadcast from LDS; K-halves via LDS partials.
__global__ __launch_bounds__(256, 3) void k_qkvq(
    const float* __restrict__ x, const float* __restrict__ Wq,
    const float* __restrict__ Wk, const float* __restrict__ Wv,
    const float* __restrict__ qp, float* __restrict__ ws) {
  __shared__ float xs[16][128];     // 8 KB
  __shared__ float th[2][16][128];  // 16 KB partials per K-half
  const int t = threadIdx.x;
  const int tile = blockIdx.x;  // 0..127 (16 rows)
  const int m = blockIdx.y;     // 0..2
  const float* W = (m == 0) ? Wq : (m == 1) ? Wk : Wv;
  const int e = t & 127, half = t >> 7;
  float4 w[16];
  {
    const float4* wr = (const float4*)W + (size_t)e * 32 + half * 16;
#pragma unroll
    for (int i = 0; i < 16; ++i) w[i] = wr[i];  // in flight during staging
  }
  {
    const float4* xg = (const float4*)(x + (size_t)tile * 2048);
    float4* xv = (float4*)&xs[0][0];
    xv[t] = xg[t];
    xv[t + 256] = xg[t + 256];
  }
  __syncthreads();
  const float4* xs4 = (const float4*)&xs[0][0];
#pragma unroll
  for (int r = 0; r < 16; ++r) {
    float a = 0.f;
    const float4* xr = xs4 + r * 32 + half * 16;
#pragma unroll
    for (int i = 0; i < 16; ++i) {
      float4 xv = xr[i];  // LDS broadcast (wave-uniform addr)
      a = fmaf(xv.x, w[i].x, a);
      a = fmaf(xv.y, w[i].y, a);
      a = fmaf(xv.z, w[i].z, a);
      a = fmaf(xv.w, w[i].w, a);
    }
    th[half][r][e] = a;  // lanes e-consecutive: conflict-free
  }
  __syncthreads();
  // quantum tail: 512 tasks (16 rows x 32 half-heads); 2 rows per thread.
  const int cg = t & 31;
  const int r0 = (t >> 5) * 2;
  const int j0 = (cg & 1) * 4;
  float4 qs4;
  qs4.x = qp[j0 + 0] + qp[8 + j0 + 0];
  qs4.y = qp[j0 + 1] + qp[8 + j0 + 1];
  qs4.z = qp[j0 + 2] + qp[8 + j0 + 2];
  qs4.w = qp[j0 + 3] + qp[8 + j0 + 3];
  const bool hi = (cg & 1) != 0;
  const float osc = (m == 0) ? 0.51013389376f : 1.0f;  // log2e/sqrt(8) into Q
  const float4* th4 = (const float4*)&th[0][0][0];
#pragma unroll
  for (int rr = 0; rr < 2; ++rr) {
    int r = r0 + rr;
    float4 s0 = th4[r * 32 + cg];
    float4 s1 = th4[512 + r * 32 + cg];
    float4 a4 = make_float4(s0.x + s1.x, s0.y + s1.y, s0.z + s1.z, s0.w + s1.w);
    float4 c;
    c.x = __cosf(a4.x + qs4.x);
    c.y = __cosf(a4.y + qs4.y);
    c.z = __cosf(a4.z + qs4.z);
    c.w = __cosf(a4.w + qs4.w);
    float4 u;  // local prefix: (c0, c1, c0c2, c1c3) in this half's numbering
    u.x = c.x; u.y = c.y; u.z = c.x * c.z; u.w = c.y * c.w;
    float gz = __shfl_xor(u.z, 1);  // even lane's (c0*c2) -> odd lane
    float gw = __shfl_xor(u.w, 1);  // even lane's (c1*c3) -> odd lane
    float mz = hi ? gz : 1.f, mw = hi ? gw : 1.f;
    float4 o;
    o.x = u.x * mz * osc; o.y = u.y * mw * osc;
    o.z = u.z * mz * osc; o.w = u.w * mw * osc;
    int row = tile * 16 + r;
    *(float4*)(ws + (size_t)m * MATSZ + (size_t)row * 128 + cg * 4) = o;
  }
}

// ---------------- k_fused: attention + output projection ---------------------
// grid 256: (b = bid>>6, 8-row s-tile = bid&63). 256 thr = 16 heads x 16 k-parts.
// K/V of the whole batch streamed in 64-key chunks (all heads), double-buffered
// LDS with T14 split staging (loads before compute, LDS writes after).
// Out-proj runs in-block from LDS (block holds all heads of its rows).
__global__ __launch_bounds__(256, 1) void k_fused(
    const float* __restrict__ ws, const float* __restrict__ Wo,
    float* __restrict__ out) {
  extern __shared__ float sm[];  // [K0|V0|K1|V1|qs] = 4*CH + 1024 floats
  const int t = threadIdx.x;
  const int b = blockIdx.x >> 6;
  const int row0 = (blockIdx.x & 63) * 8;  // local row in batch
  const float* Qg = ws + ((size_t)(b * 512 + row0)) * 128;
  const float* Kg = ws + MATSZ + (size_t)b * 512 * 128;
  const float* Vg = ws + 2 * (size_t)MATSZ + (size_t)b * 512 * 128;
  float* qs = sm + 4 * CH;
  // prologue: stage Q (8x128) + chunk 0 into buf0
  ((float4*)qs)[t] = ((const float4*)Qg)[t];
  {
    const float4* Ks = (const float4*)Kg;
    const float4* Vs = (const float4*)Vg;
#pragma unroll
    for (int i = 0; i < 8; ++i) {
      int idx = t + i * 256;  // f4 index within 64x128 chunk
      int r = idx >> 5, c4 = idx & 31;
      *(float4*)(sm + (size_t)r * LDK + c4 * 4) = Ks[idx];
      *(float4*)(sm + CH + (size_t)r * LDK + c4 * 4) = Vs[idx];
    }
  }
  __syncthreads();
  const int h = t >> 4, ko = t & 15;
  float4 qa[8], qb[8];  // Q for head h, 8 rows (pre-scaled in k_qkvq)
#pragma unroll
  for (int r = 0; r < 8; ++r) {
    qa[r] = *(const float4*)(qs + r * 128 + h * 8);      // broadcast per h
    qb[r] = *(const float4*)(qs + r * 128 + h * 8 + 4);
  }
  float l[8];
  float a[8][8];
#pragma unroll
  for (int r = 0; r < 8; ++r) {
    l[r] = 0.f;
#pragma unroll
    for (int j = 0; j < 8; ++j) a[r][j] = 0.f;
  }
  for (int c = 0; c < 8; ++c) {
    const float* KB = sm + (size_t)(c & 1) * (2 * CH);
    const float* VB = KB + CH;
    const bool more = (c < 7);
    float4 tk[8], tv[8];
    if (more) {  // T14: issue next-chunk loads before compute
      const float4* Ks = (const float4*)Kg + (size_t)(c + 1) * 2048;
      const float4* Vs = (const float4*)Vg + (size_t)(c + 1) * 2048;
#pragma unroll
      for (int i = 0; i < 8; ++i) {
        int idx = t + i * 256;
        tk[i] = Ks[idx];
        tv[i] = Vs[idx];
      }
    }
#pragma unroll
    for (int i = 0; i < 4; ++i) {
      int j = i * 16 + ko;
      float4 kx = *(const float4*)(KB + j * LDK + h * 8);
      float4 ky = *(const float4*)(KB + j * LDK + h * 8 + 4);
      float4 vx = *(const float4*)(VB + j * LDK + h * 8);
      float4 vy = *(const float4*)(VB + j * LDK + h * 8 + 4);
#pragma unroll
      for (int r = 0; r < 8; ++r) {
        float s = qa[r].x * kx.x + qa[r].y * kx.y + qa[r].z * kx.z +
                  qa[r].w * kx.w + qb[r].x * ky.x + qb[r].y * ky.y +
                  qb[r].z * ky.z + qb[r].w * ky.w;
        float p = exp2f(s);  // |orig score| <= 2.83: no max subtraction
        l[r] += p;
        a[r][0] = fmaf(p, vx.x, a[r][0]);
        a[r][1] = fmaf(p, vx.y, a[r][1]);
        a[r][2] = fmaf(p, vx.z, a[r][2]);
        a[r][3] = fmaf(p, vx.w, a[r][3]);
        a[r][4] = fmaf(p, vy.x, a[r][4]);
        a[r][5] = fmaf(p, vy.y, a[r][5]);
        a[r][6] = fmaf(p, vy.z, a[r][6]);
        a[r][7] = fmaf(p, vy.w, a[r][7]);
      }
    }
    if (more) {  // write staged regs to the other buffer
      float* KN = sm + (size_t)((c + 1) & 1) * (2 * CH);
#pragma unroll
      for (int i = 0; i < 8; ++i) {
        int idx = t + i * 256;
        int r = idx >> 5, c4 = idx & 31;
        *(float4*)(KN + (size_t)r * LDK + c4 * 4) = tk[i];
        *(float4*)(KN + CH + (size_t)r * LDK + c4 * 4) = tv[i];
      }
    }
    __syncthreads();
  }
  // Wo fragment prefetch (hides L2 under the shuffle reduction)
  const int e = t & 127, half = t >> 7;
  float4 w[16];
  {
    const float4* wr = (const float4*)Wo + (size_t)e * 32 + half * 16;
#pragma unroll
    for (int i = 0; i < 16; ++i) w[i] = wr[i];
  }
  // reduce over 16 k-parts (in-wave, 16-lane groups)
#pragma unroll
  for (int mm = 1; mm <= 8; mm <<= 1) {
#pragma unroll
    for (int r = 0; r < 8; ++r) {
      l[r] += __shfl_xor(l[r], mm);
#pragma unroll
      for (int j = 0; j < 8; ++j) a[r][j] += __shfl_xor(a[r][j], mm);
    }
  }
  if (ko == 0) {  // aout[8][128] at sm[0..1023] (buffers are dead now)
#pragma unroll
    for (int r = 0; r < 8; ++r) {
      float inv = 1.f / l[r];
      float* d = sm + r * 128 + h * 8;
      ((float4*)d)[0] = make_float4(a[r][0] * inv, a[r][1] * inv,
                                    a[r][2] * inv, a[r][3] * inv);
      ((float4*)d)[1] = make_float4(a[r][4] * inv, a[r][5] * inv,
                                    a[r][6] * inv, a[r][7] * inv);
    }
  }
  __syncthreads();
  // out-proj: thread = (col e, K-half); partials via LDS, then combine.
  float* th = sm + 1024;  // [2][8][128]
  const float4* at4 = (const float4*)sm;
#pragma unroll
  for (int r = 0; r < 8; ++r) {
    float acc = 0.f;
    const float4* ar = at4 + r * 32 + half * 16;
#pragma unroll
    for (int i = 0; i < 16; ++i) {
      float4 av = ar[i];  // LDS broadcast
      acc = fmaf(av.x, w[i].x, acc);
      acc = fmaf(av.y, w[i].y, acc);
      acc = fmaf(av.z, w[i].z, acc);
      acc = fmaf(av.w, w[i].w, acc);
    }
    th[(half * 8 + r) * 128 + e] = acc;
  }
  __syncthreads();
  {
    const int cg = t & 31, rg = t >> 5;
    const float4* th4 = (const float4*)th;
    float4 p0 = th4[rg * 32 + cg];
    float4 p1 = th4[256 + rg * 32 + cg];
    float4 o = make_float4(p0.x + p1.x, p0.y + p1.y, p0.z + p1.z, p0.w + p1.w);
    *(float4*)(out + ((size_t)(b * 512 + row0 + rg)) * 128 + cg * 4) = o;
  }
}

extern "C" void kernel_launch(void* const* d_in, const int* in_sizes, int n_in,
                              void* d_out, int out_size, void* d_ws, size_t ws_size,
                              hipStream_t stream) {
  const float* x  = (const float*)d_in[0];
  const float* Wq = (const float*)d_in[1];
  const float* Wk = (const float*)d_in[2];
  const float* Wv = (const float*)d_in[3];
  const float* Wo = (const float*)d_in[4];
  const float* qp = (const float*)d_in[5];
  float* out = (float*)d_out;
  float* ws = (float*)d_ws;

  const size_t smem = (4 * CH + 1024) * sizeof(float);  // 139264 B
  static int attr_done = 0;
  (void)hipFuncSetAttribute((const void*)k_fused,
                            hipFuncAttributeMaxDynamicSharedMemorySize,
                            (int)smem);
  (void)attr_done;

  hipLaunchKernelGGL(k_qkvq, dim3(128, 3), dim3(256), 0, stream,
                     x, Wq, Wk, Wv, qp, ws);
  hipLaunchKernelGGL(k_fused, dim3(256), dim3(256), smem, stream,
                     ws, Wo, out);
}

// Round 9
// 52.627 us; speedup vs baseline: 1.3898x; 1.3898x over previous
//
#include <hip/hip_runtime.h>
#include <cmath>

#define MATSZ 262144  // 2048 * 128
// ws: qkv[m][2048][128] row-major; m: 0=Q (pre-scaled by log2e/sqrt8), 1=K, 2=V.
// Column e = h*8 + j (head-blocked) == natural reshape(B,S,H,dk).

// ---------------- k_qkvq: QKV projection + quantum closed form ---------------
// 16-row tiles, grid (128,3). thread = (col e, K-half); W row fragment in regs
// (issued first, L2-hot); x rows broadcast from LDS; K-halves via LDS partials.
__global__ __launch_bounds__(256, 3) void k_qkvq(
    const float* __restrict__ x, const float* __restrict__ Wq,
    const float* __restrict__ Wk, const float* __restrict__ Wv,
    const float* __restrict__ qp, float* __restrict__ ws) {
  __shared__ float xs[16][128];     // 8 KB
  __shared__ float th[2][16][128];  // 16 KB partials per K-half
  const int t = threadIdx.x;
  const int tile = blockIdx.x;  // 0..127 (16 rows)
  const int m = blockIdx.y;     // 0..2
  const float* W = (m == 0) ? Wq : (m == 1) ? Wk : Wv;
  const int e = t & 127, half = t >> 7;
  float4 w[16];
  {
    const float4* wr = (const float4*)W + (size_t)e * 32 + half * 16;
#pragma unroll
    for (int i = 0; i < 16; ++i) w[i] = wr[i];  // in flight during staging
  }
  {
    const float4* xg = (const float4*)(x + (size_t)tile * 2048);
    float4* xv = (float4*)&xs[0][0];
    xv[t] = xg[t];
    xv[t + 256] = xg[t + 256];
  }
  __syncthreads();
  const float4* xs4 = (const float4*)&xs[0][0];
#pragma unroll
  for (int r = 0; r < 16; ++r) {
    float a = 0.f;
    const float4* xr = xs4 + r * 32 + half * 16;
#pragma unroll
    for (int i = 0; i < 16; ++i) {
      float4 xv = xr[i];  // LDS broadcast (wave-uniform addr)
      a = fmaf(xv.x, w[i].x, a);
      a = fmaf(xv.y, w[i].y, a);
      a = fmaf(xv.z, w[i].z, a);
      a = fmaf(xv.w, w[i].w, a);
    }
    th[half][r][e] = a;  // lanes e-consecutive: conflict-free
  }
  __syncthreads();
  // quantum tail: 512 tasks (16 rows x 32 half-heads); 2 rows per thread.
  const int cg = t & 31;
  const int r0 = (t >> 5) * 2;
  const int j0 = (cg & 1) * 4;
  float4 qs4;
  qs4.x = qp[j0 + 0] + qp[8 + j0 + 0];
  qs4.y = qp[j0 + 1] + qp[8 + j0 + 1];
  qs4.z = qp[j0 + 2] + qp[8 + j0 + 2];
  qs4.w = qp[j0 + 3] + qp[8 + j0 + 3];
  const bool hi = (cg & 1) != 0;
  const float osc = (m == 0) ? 0.51013389376f : 1.0f;  // log2e/sqrt(8) into Q
  const float4* th4 = (const float4*)&th[0][0][0];
#pragma unroll
  for (int rr = 0; rr < 2; ++rr) {
    int r = r0 + rr;
    float4 s0 = th4[r * 32 + cg];
    float4 s1 = th4[512 + r * 32 + cg];
    float4 a4 = make_float4(s0.x + s1.x, s0.y + s1.y, s0.z + s1.z, s0.w + s1.w);
    float4 c;
    c.x = __cosf(a4.x + qs4.x);
    c.y = __cosf(a4.y + qs4.y);
    c.z = __cosf(a4.z + qs4.z);
    c.w = __cosf(a4.w + qs4.w);
    float4 u;  // local prefix: (c0, c1, c0c2, c1c3) in this half's numbering
    u.x = c.x; u.y = c.y; u.z = c.x * c.z; u.w = c.y * c.w;
    float gz = __shfl_xor(u.z, 1);  // even lane's (c0*c2) -> odd lane
    float gw = __shfl_xor(u.w, 1);  // even lane's (c1*c3) -> odd lane
    float mz = hi ? gz : 1.f, mw = hi ? gw : 1.f;
    float4 o;
    o.x = u.x * mz * osc; o.y = u.y * mw * osc;
    o.z = u.z * mz * osc; o.w = u.w * mw * osc;
    int row = tile * 16 + r;
    *(float4*)(ws + (size_t)m * MATSZ + (size_t)row * 128 + cg * 4) = o;
  }
}

// ---------------- k_fused: attention + output projection ---------------------
// grid 512 = (b, 4-row s-tile); 2 blocks/CU (LDS 72 KB). 256 thr = 16 h x 16 ko.
// K/V streamed in 32-key double-buffered chunks, reg-staged (4+4 float4/thread,
// loads issued before compute). Out-proj in-block (all heads local).
__global__ __launch_bounds__(256, 2) void k_fused(
    const float* __restrict__ ws, const float* __restrict__ Wo,
    float* __restrict__ out) {
  __shared__ float kbuf[2][32 * 128];  // 16 KB each
  __shared__ float vbuf[2][32 * 128];
  __shared__ float qs[4 * 128];        // 2 KB
  __shared__ float aouts[4 * 128];     // 2 KB
  __shared__ float th[2][4][128];      // 4 KB
  const int t = threadIdx.x;
  const int b = blockIdx.x >> 7;       // 0..3
  const int row0 = (blockIdx.x & 127) * 4;
  const float* Qg = ws + ((size_t)(b * 512 + row0)) * 128;
  const float* Kg = ws + MATSZ + (size_t)b * 512 * 128;
  const float* Vg = ws + 2 * (size_t)MATSZ + (size_t)b * 512 * 128;
  if (t < 128) ((float4*)qs)[t] = ((const float4*)Qg)[t];
  {  // stage chunk 0
    const float4* Ks = (const float4*)Kg;
    const float4* Vs = (const float4*)Vg;
#pragma unroll
    for (int i = 0; i < 4; ++i) {
      ((float4*)kbuf[0])[t + i * 256] = Ks[t + i * 256];
      ((float4*)vbuf[0])[t + i * 256] = Vs[t + i * 256];
    }
  }
  __syncthreads();
  const int h = t >> 4, ko = t & 15;
  float4 qa[4], qb[4];  // pre-scaled in k_qkvq
#pragma unroll
  for (int r = 0; r < 4; ++r) {
    qa[r] = *(const float4*)(qs + r * 128 + h * 8);
    qb[r] = *(const float4*)(qs + r * 128 + h * 8 + 4);
  }
  float l[4] = {0.f, 0.f, 0.f, 0.f};
  float a[4][8];
#pragma unroll
  for (int r = 0; r < 4; ++r)
#pragma unroll
    for (int j = 0; j < 8; ++j) a[r][j] = 0.f;
  for (int c = 0; c < 16; ++c) {
    const float* KB = kbuf[c & 1];
    const float* VB = vbuf[c & 1];
    const bool more = (c < 15);
    float4 tk[4], tv[4];
    if (more) {  // T14: issue next-chunk loads before compute
      const float4* Ks = (const float4*)Kg + (size_t)(c + 1) * 1024;
      const float4* Vs = (const float4*)Vg + (size_t)(c + 1) * 1024;
#pragma unroll
      for (int i = 0; i < 4; ++i) {
        tk[i] = Ks[t + i * 256];
        tv[i] = Vs[t + i * 256];
      }
    }
#pragma unroll
    for (int i = 0; i < 2; ++i) {
      int j = i * 16 + ko;
      float4 kx = *(const float4*)(KB + j * 128 + h * 8);
      float4 ky = *(const float4*)(KB + j * 128 + h * 8 + 4);
      float4 vx = *(const float4*)(VB + j * 128 + h * 8);
      float4 vy = *(const float4*)(VB + j * 128 + h * 8 + 4);
#pragma unroll
      for (int r = 0; r < 4; ++r) {
        float s = qa[r].x * kx.x + qa[r].y * kx.y + qa[r].z * kx.z +
                  qa[r].w * kx.w + qb[r].x * ky.x + qb[r].y * ky.y +
                  qb[r].z * ky.z + qb[r].w * ky.w;
        float p = exp2f(s);  // |orig score| <= 2.83: no max subtraction
        l[r] += p;
        a[r][0] = fmaf(p, vx.x, a[r][0]);
        a[r][1] = fmaf(p, vx.y, a[r][1]);
        a[r][2] = fmaf(p, vx.z, a[r][2]);
        a[r][3] = fmaf(p, vx.w, a[r][3]);
        a[r][4] = fmaf(p, vy.x, a[r][4]);
        a[r][5] = fmaf(p, vy.y, a[r][5]);
        a[r][6] = fmaf(p, vy.z, a[r][6]);
        a[r][7] = fmaf(p, vy.w, a[r][7]);
      }
    }
    if (more) {  // write next buffer (distinct from the one being read)
      float* KN = kbuf[(c + 1) & 1];
      float* VN = vbuf[(c + 1) & 1];
#pragma unroll
      for (int i = 0; i < 4; ++i) {
        ((float4*)KN)[t + i * 256] = tk[i];
        ((float4*)VN)[t + i * 256] = tv[i];
      }
    }
    __syncthreads();
  }
  // Wo fragment load now (attention regs dead; hides L2 under the reduce)
  const int e = t & 127, half = t >> 7;
  float4 w[16];
  {
    const float4* wr = (const float4*)Wo + (size_t)e * 32 + half * 16;
#pragma unroll
    for (int i = 0; i < 16; ++i) w[i] = wr[i];
  }
#pragma unroll
  for (int mm = 1; mm <= 8; mm <<= 1) {  // reduce over 16 k-parts (in-wave)
#pragma unroll
    for (int r = 0; r < 4; ++r) {
      l[r] += __shfl_xor(l[r], mm);
#pragma unroll
      for (int j = 0; j < 8; ++j) a[r][j] += __shfl_xor(a[r][j], mm);
    }
  }
  if (ko == 0) {  // 16 lanes: 4 per wave, distinct bank-quads
#pragma unroll
    for (int r = 0; r < 4; ++r) {
      float inv = 1.f / l[r];
      float* d = aouts + r * 128 + h * 8;
      ((float4*)d)[0] = make_float4(a[r][0] * inv, a[r][1] * inv,
                                    a[r][2] * inv, a[r][3] * inv);
      ((float4*)d)[1] = make_float4(a[r][4] * inv, a[r][5] * inv,
                                    a[r][6] * inv, a[r][7] * inv);
    }
  }
  __syncthreads();
  // out-proj: thread = (col e, K-half); partials via LDS, then combine.
  const float4* at4 = (const float4*)aouts;
#pragma unroll
  for (int r = 0; r < 4; ++r) {
    float acc = 0.f;
    const float4* ar = at4 + r * 32 + half * 16;
#pragma unroll
    for (int i = 0; i < 16; ++i) {
      float4 av = ar[i];  // LDS broadcast
      acc = fmaf(av.x, w[i].x, acc);
      acc = fmaf(av.y, w[i].y, acc);
      acc = fmaf(av.z, w[i].z, acc);
      acc = fmaf(av.w, w[i].w, acc);
    }
    th[half][r][e] = acc;
  }
  __syncthreads();
  {
    const int rr = t >> 7;  // 0..1 -> rows rr and rr+2
#pragma unroll
    for (int k = 0; k < 2; ++k) {
      int r = rr + k * 2;
      float o = th[0][r][e] + th[1][r][e];
      out[((size_t)(b * 512 + row0 + r)) * 128 + e] = o;
    }
  }
}

extern "C" void kernel_launch(void* const* d_in, const int* in_sizes, int n_in,
                              void* d_out, int out_size, void* d_ws, size_t ws_size,
                              hipStream_t stream) {
  const float* x  = (const float*)d_in[0];
  const float* Wq = (const float*)d_in[1];
  const float* Wk = (const float*)d_in[2];
  const float* Wv = (const float*)d_in[3];
  const float* Wo = (const float*)d_in[4];
  const float* qp = (const float*)d_in[5];
  float* out = (float*)d_out;
  float* ws = (float*)d_ws;

  hipLaunchKernelGGL(k_qkvq, dim3(128, 3), dim3(256), 0, stream,
                     x, Wq, Wk, Wv, qp, ws);
  hipLaunchKernelGGL(k_fused, dim3(512), dim3(256), 0, stream, ws, Wo, out);
}

// Round 10
// 47.125 us; speedup vs baseline: 1.5521x; 1.1168x over previous
//
#include <hip/hip_runtime.h>
#include <cmath>

#define MATSZ 262144  // 2048 * 128
// ws: qkv[m][2048][128] row-major; m: 0=Q (pre-scaled by log2e/sqrt8), 1=K, 2=V.
// Column e = h*8 + j (head-blocked) == natural reshape(B,S,H,dk).

// ---------------- k_qkvq: QKV projection + quantum closed form ---------------
// 16-row tiles, grid (128,3). thread = (col e, K-half); W row fragment in regs
// (issued first, L2-hot); x rows broadcast from LDS; K-halves via LDS partials.
__global__ __launch_bounds__(256, 3) void k_qkvq(
    const float* __restrict__ x, const float* __restrict__ Wq,
    const float* __restrict__ Wk, const float* __restrict__ Wv,
    const float* __restrict__ qp, float* __restrict__ ws) {
  __shared__ float xs[16][128];     // 8 KB
  __shared__ float th[2][16][128];  // 16 KB partials per K-half
  const int t = threadIdx.x;
  const int tile = blockIdx.x;  // 0..127 (16 rows)
  const int m = blockIdx.y;     // 0..2
  const float* W = (m == 0) ? Wq : (m == 1) ? Wk : Wv;
  const int e = t & 127, half = t >> 7;
  float4 w[16];
  {
    const float4* wr = (const float4*)W + (size_t)e * 32 + half * 16;
#pragma unroll
    for (int i = 0; i < 16; ++i) w[i] = wr[i];  // in flight during staging
  }
  {
    const float4* xg = (const float4*)(x + (size_t)tile * 2048);
    float4* xv = (float4*)&xs[0][0];
    xv[t] = xg[t];
    xv[t + 256] = xg[t + 256];
  }
  __syncthreads();
  const float4* xs4 = (const float4*)&xs[0][0];
#pragma unroll
  for (int r = 0; r < 16; ++r) {
    float a = 0.f;
    const float4* xr = xs4 + r * 32 + half * 16;
#pragma unroll
    for (int i = 0; i < 16; ++i) {
      float4 xv = xr[i];  // LDS broadcast (wave-uniform addr)
      a = fmaf(xv.x, w[i].x, a);
      a = fmaf(xv.y, w[i].y, a);
      a = fmaf(xv.z, w[i].z, a);
      a = fmaf(xv.w, w[i].w, a);
    }
    th[half][r][e] = a;  // lanes e-consecutive: conflict-free
  }
  __syncthreads();
  // quantum tail: 512 tasks (16 rows x 32 half-heads); 2 rows per thread.
  const int cg = t & 31;
  const int r0 = (t >> 5) * 2;
  const int j0 = (cg & 1) * 4;
  float4 qs4;
  qs4.x = qp[j0 + 0] + qp[8 + j0 + 0];
  qs4.y = qp[j0 + 1] + qp[8 + j0 + 1];
  qs4.z = qp[j0 + 2] + qp[8 + j0 + 2];
  qs4.w = qp[j0 + 3] + qp[8 + j0 + 3];
  const bool hi = (cg & 1) != 0;
  const float osc = (m == 0) ? 0.51013389376f : 1.0f;  // log2e/sqrt(8) into Q
  const float4* th4 = (const float4*)&th[0][0][0];
#pragma unroll
  for (int rr = 0; rr < 2; ++rr) {
    int r = r0 + rr;
    float4 s0 = th4[r * 32 + cg];
    float4 s1 = th4[512 + r * 32 + cg];
    float4 a4 = make_float4(s0.x + s1.x, s0.y + s1.y, s0.z + s1.z, s0.w + s1.w);
    float4 c;
    c.x = __cosf(a4.x + qs4.x);
    c.y = __cosf(a4.y + qs4.y);
    c.z = __cosf(a4.z + qs4.z);
    c.w = __cosf(a4.w + qs4.w);
    float4 u;  // local prefix: (c0, c1, c0c2, c1c3) in this half's numbering
    u.x = c.x; u.y = c.y; u.z = c.x * c.z; u.w = c.y * c.w;
    float gz = __shfl_xor(u.z, 1);  // even lane's (c0*c2) -> odd lane
    float gw = __shfl_xor(u.w, 1);  // even lane's (c1*c3) -> odd lane
    float mz = hi ? gz : 1.f, mw = hi ? gw : 1.f;
    float4 o;
    o.x = u.x * mz * osc; o.y = u.y * mw * osc;
    o.z = u.z * mz * osc; o.w = u.w * mw * osc;
    int row = tile * 16 + r;
    *(float4*)(ws + (size_t)m * MATSZ + (size_t)row * 128 + cg * 4) = o;
  }
}

// ---------------- k_fused: attention + output projection ---------------------
// grid 512 = (b, 4-row s-tile); 2 blocks/CU (LDS 72 KB). 256 thr = 16 h x 16 ko.
// K/V streamed in 32-key double-buffered chunks, reg-staged.
// T2 XOR swizzle: element (key r, f4-col c4) lives at f4 slot r*32 + (c4^(r&7))
// -> reads land 8 lanes / bank-quad with distinct addresses = b128 floor,
//    zero extra conflicts (fixes R8's 16-way, SQ_LDS_BANK_CONFLICT 917K).
__global__ __launch_bounds__(256, 2) void k_fused(
    const float* __restrict__ ws, const float* __restrict__ Wo,
    float* __restrict__ out) {
  __shared__ float kbuf[2][32 * 128];  // 16 KB each, swizzled
  __shared__ float vbuf[2][32 * 128];
  __shared__ float qs[4 * 128];        // 2 KB
  __shared__ float aouts[4 * 128];     // 2 KB
  __shared__ float th[2][4][128];      // 4 KB
  const int t = threadIdx.x;
  const int b = blockIdx.x >> 7;       // 0..3
  const int row0 = (blockIdx.x & 127) * 4;
  const float* Qg = ws + ((size_t)(b * 512 + row0)) * 128;
  const float* Kg = ws + MATSZ + (size_t)b * 512 * 128;
  const float* Vg = ws + 2 * (size_t)MATSZ + (size_t)b * 512 * 128;
  const int sr = t >> 5, sc = t & 31;       // staging (row-base, col) of f4 grid
  if (t < 128) ((float4*)qs)[t] = ((const float4*)Qg)[t];
  {  // stage chunk 0 (swizzled)
    const float4* Ks = (const float4*)Kg;
    const float4* Vs = (const float4*)Vg;
#pragma unroll
    for (int i = 0; i < 4; ++i) {
      int r = sr + i * 8;
      int d = r * 32 + (sc ^ (r & 7));
      ((float4*)kbuf[0])[d] = Ks[r * 32 + sc];
      ((float4*)vbuf[0])[d] = Vs[r * 32 + sc];
    }
  }
  __syncthreads();
  const int h = t >> 4, ko = t & 15;
  float4 qa[4], qb[4];  // pre-scaled in k_qkvq
#pragma unroll
  for (int r = 0; r < 4; ++r) {
    qa[r] = *(const float4*)(qs + r * 128 + h * 8);
    qb[r] = *(const float4*)(qs + r * 128 + h * 8 + 4);
  }
  float l[4] = {0.f, 0.f, 0.f, 0.f};
  float a[4][8];
#pragma unroll
  for (int r = 0; r < 4; ++r)
#pragma unroll
    for (int j = 0; j < 8; ++j) a[r][j] = 0.f;
  for (int c = 0; c < 16; ++c) {
    const float4* KB = (const float4*)kbuf[c & 1];
    const float4* VB = (const float4*)vbuf[c & 1];
    const bool more = (c < 15);
    float4 tk[4], tv[4];
    if (more) {  // T14: issue next-chunk loads before compute
      const float4* Ks = (const float4*)Kg + (size_t)(c + 1) * 1024;
      const float4* Vs = (const float4*)Vg + (size_t)(c + 1) * 1024;
#pragma unroll
      for (int i = 0; i < 4; ++i) {
        tk[i] = Ks[t + i * 256];
        tv[i] = Vs[t + i * 256];
      }
    }
#pragma unroll
    for (int i = 0; i < 2; ++i) {
      int j = i * 16 + ko;
      int base = j * 32;
      int sw = j & 7;
      float4 kx = KB[base + ((h * 2) ^ sw)];
      float4 ky = KB[base + ((h * 2 + 1) ^ sw)];
      float4 vx = VB[base + ((h * 2) ^ sw)];
      float4 vy = VB[base + ((h * 2 + 1) ^ sw)];
#pragma unroll
      for (int r = 0; r < 4; ++r) {
        float s = qa[r].x * kx.x + qa[r].y * kx.y + qa[r].z * kx.z +
                  qa[r].w * kx.w + qb[r].x * ky.x + qb[r].y * ky.y +
                  qb[r].z * ky.z + qb[r].w * ky.w;
        float p = exp2f(s);  // |orig score| <= 2.83: no max subtraction
        l[r] += p;
        a[r][0] = fmaf(p, vx.x, a[r][0]);
        a[r][1] = fmaf(p, vx.y, a[r][1]);
        a[r][2] = fmaf(p, vx.z, a[r][2]);
        a[r][3] = fmaf(p, vx.w, a[r][3]);
        a[r][4] = fmaf(p, vy.x, a[r][4]);
        a[r][5] = fmaf(p, vy.y, a[r][5]);
        a[r][6] = fmaf(p, vy.z, a[r][6]);
        a[r][7] = fmaf(p, vy.w, a[r][7]);
      }
    }
    if (more) {  // write next buffer (distinct from the one being read)
      float4* KN = (float4*)kbuf[(c + 1) & 1];
      float4* VN = (float4*)vbuf[(c + 1) & 1];
#pragma unroll
      for (int i = 0; i < 4; ++i) {
        int r = sr + i * 8;
        int d = r * 32 + (sc ^ (r & 7));
        KN[d] = tk[i];
        VN[d] = tv[i];
      }
    }
    __syncthreads();
  }
  // Wo fragment load now (attention regs mostly dead; hides L2 under reduce)
  const int e = t & 127, half = t >> 7;
  float4 w[16];
  {
    const float4* wr = (const float4*)Wo + (size_t)e * 32 + half * 16;
#pragma unroll
    for (int i = 0; i < 16; ++i) w[i] = wr[i];
  }
#pragma unroll
  for (int mm = 1; mm <= 8; mm <<= 1) {  // reduce over 16 k-parts (in-wave)
#pragma unroll
    for (int r = 0; r < 4; ++r) {
      l[r] += __shfl_xor(l[r], mm);
#pragma unroll
      for (int j = 0; j < 8; ++j) a[r][j] += __shfl_xor(a[r][j], mm);
    }
  }
  if (ko == 0) {  // 16 lanes: 4 per wave, distinct bank-quads
#pragma unroll
    for (int r = 0; r < 4; ++r) {
      float inv = 1.f / l[r];
      float* d = aouts + r * 128 + h * 8;
      ((float4*)d)[0] = make_float4(a[r][0] * inv, a[r][1] * inv,
                                    a[r][2] * inv, a[r][3] * inv);
      ((float4*)d)[1] = make_float4(a[r][4] * inv, a[r][5] * inv,
                                    a[r][6] * inv, a[r][7] * inv);
    }
  }
  __syncthreads();
  // out-proj: thread = (col e, K-half); partials via LDS, then combine.
  const float4* at4 = (const float4*)aouts;
#pragma unroll
  for (int r = 0; r < 4; ++r) {
    float acc = 0.f;
    const float4* ar = at4 + r * 32 + half * 16;
#pragma unroll
    for (int i = 0; i < 16; ++i) {
      float4 av = ar[i];  // LDS broadcast
      acc = fmaf(av.x, w[i].x, acc);
      acc = fmaf(av.y, w[i].y, acc);
      acc = fmaf(av.z, w[i].z, acc);
      acc = fmaf(av.w, w[i].w, acc);
    }
    th[half][r][e] = acc;
  }
  __syncthreads();
  {
    const int rr = t >> 7;  // 0..1 -> rows rr and rr+2
#pragma unroll
    for (int k = 0; k < 2; ++k) {
      int r = rr + k * 2;
      float o = th[0][r][e] + th[1][r][e];
      out[((size_t)(b * 512 + row0 + r)) * 128 + e] = o;
    }
  }
}

extern "C" void kernel_launch(void* const* d_in, const int* in_sizes, int n_in,
                              void* d_out, int out_size, void* d_ws, size_t ws_size,
                              hipStream_t stream) {
  const float* x  = (const float*)d_in[0];
  const float* Wq = (const float*)d_in[1];
  const float* Wk = (const float*)d_in[2];
  const float* Wv = (const float*)d_in[3];
  const float* Wo = (const float*)d_in[4];
  const float* qp = (const float*)d_in[5];
  float* out = (float*)d_out;
  float* ws = (float*)d_ws;

  hipLaunchKernelGGL(k_qkvq, dim3(128, 3), dim3(256), 0, stream,
                     x, Wq, Wk, Wv, qp, ws);
  hipLaunchKernelGGL(k_fused, dim3(512), dim3(256), 0, stream, ws, Wo, out);
}

// Round 11
// 46.665 us; speedup vs baseline: 1.5674x; 1.0099x over previous
//
#include <hip/hip_runtime.h>
#include <cmath>

#define MATSZ 262144  // 2048 * 128
// ws: Q at [0, MATSZ): row-major [row][128], pre-scaled by log2e/sqrt(8).
//     K at [MATSZ, 2*MATSZ): [bh][s][8].  V at [2*MATSZ, 3*MATSZ): [bh][s][8].
//     aout at [3*MATSZ, 4*MATSZ): row-major [row][128].

// ---------------- k_qkvq v3: projection + quantum, zero LDS ------------------
// 8-row tiles, grid (256,3), 128 threads. Thread = one output column e:
// full W row (128 floats) in VGPRs; x rows read as wave-uniform float4 loads
// (scalarizable -> s_load + SGPR operand FMA). Quantum prefix-product via two
// in-wave shuffles across the 8 lanes of each head. No barriers at all.
__global__ __launch_bounds__(128) void k_qkvq(
    const float* __restrict__ x, const float* __restrict__ Wq,
    const float* __restrict__ Wk, const float* __restrict__ Wv,
    const float* __restrict__ qp, float* __restrict__ ws) {
  const int e = threadIdx.x;    // 0..127 output column
  const int tile = blockIdx.x;  // 0..255 (8 rows)
  const int m = blockIdx.y;     // 0=Q 1=K 2=V
  const float* W = (m == 0) ? Wq : (m == 1) ? Wk : Wv;
  float4 w[32];
  {
    const float4* wr = (const float4*)W + (size_t)e * 32;
#pragma unroll
    for (int i = 0; i < 32; ++i) w[i] = wr[i];
  }
  float acc[8];
  const float* xbase = x + (size_t)tile * 1024;
#pragma unroll
  for (int r = 0; r < 8; ++r) {
    const float4* xr = (const float4*)(xbase + r * 128);  // uniform address
    float a = 0.f;
#pragma unroll
    for (int i = 0; i < 32; ++i) {
      float4 xv = xr[i];  // wave-uniform -> scalar load, SGPR src in v_fma
      a = fmaf(xv.x, w[i].x, a);
      a = fmaf(xv.y, w[i].y, a);
      a = fmaf(xv.z, w[i].z, a);
      a = fmaf(xv.w, w[i].w, a);
    }
    acc[r] = a;
  }
  // quantum closed form. j = e&7 within head; parity prefix product
  // o_j = prod_{i<=j, i==j mod 2} c_i via Hillis-Steele (offsets 2, 4).
  const int j = e & 7;
  const int l = threadIdx.x & 63;  // lane
  const float qs = qp[j] + qp[8 + j];
  const float osc = (m == 0) ? 0.51013389376f : 1.0f;  // log2e/sqrt(8) into Q
  const int h = e >> 3;
  const int row0 = tile * 8;
  const int b = row0 >> 9;  // 8-row tile never crosses a batch boundary
#pragma unroll
  for (int r = 0; r < 8; ++r) {
    float c = __cosf(acc[r] + qs);
    float t1 = __shfl(c, l - 2);
    float x1 = (j >= 2) ? c * t1 : c;
    float t2 = __shfl(x1, l - 4);
    float x2 = (j >= 4) ? x1 * t2 : x1;
    float o = x2 * osc;
    int row = row0 + r;
    if (m == 0) {
      ws[(size_t)row * 128 + e] = o;  // Q row-major, coalesced
    } else {
      int s = row & 511;
      ws[(size_t)m * MATSZ + ((size_t)((b << 4) + h) * 512 + s) * 8 + j] = o;
    }
  }
}

// ---------------- k_attn v3: attention per (bh, 128-row q-tile) --------------
// grid (4,64) = 256 blocks, 256 thr = 32 qslots (4 rows) x 8 k-parts.
// K/V rows as lo/hi float4 arrays: access k=i*8+ko -> 8 distinct consecutive
// addresses x 8-way broadcast = conflict-free. 4 rows/thread halves LDS
// traffic vs 2-row; 8-way split -> 3-step shuffle reduce (was 4).
__global__ __launch_bounds__(256) void k_attn(float* __restrict__ ws) {
  __shared__ float4 kslo[512], kshi[512], vslo[512], vshi[512];  // 32 KB
  const int qt = blockIdx.x;  // 0..3 (128 rows)
  const int bh = blockIdx.y;  // 0..63
  const int b = bh >> 4, h = bh & 15;
  const float* Kg = ws + MATSZ + (size_t)bh * 4096;
  const float* Vg = ws + 2 * (size_t)MATSZ + (size_t)bh * 4096;
  const int t = threadIdx.x;
  {
    const float4* Kg4 = (const float4*)Kg;
    const float4* Vg4 = (const float4*)Vg;
    for (int k = t; k < 512; k += 256) {
      kslo[k] = Kg4[2 * k]; kshi[k] = Kg4[2 * k + 1];
      vslo[k] = Vg4[2 * k]; vshi[k] = Vg4[2 * k + 1];
    }
  }
  const int qslot = t >> 3, ko = t & 7;
  const int srow0 = qt * 128 + qslot * 4;  // local s of first of 4 rows
  float4 qa[4], qb[4];  // Q pre-scaled by log2e/sqrt(8) in k_qkvq
#pragma unroll
  for (int r = 0; r < 4; ++r) {
    const float* qrow = ws + ((size_t)(b * 512 + srow0 + r)) * 128 + h * 8;
    qa[r] = ((const float4*)qrow)[0];
    qb[r] = ((const float4*)qrow)[1];
  }
  __syncthreads();
  float l[4] = {0.f, 0.f, 0.f, 0.f};
  float a[4][8];
#pragma unroll
  for (int r = 0; r < 4; ++r)
#pragma unroll
    for (int j = 0; j < 8; ++j) a[r][j] = 0.f;
#pragma unroll 2
  for (int i = 0; i < 64; ++i) {
    int k = i * 8 + ko;  // 8 distinct addrs x 8-way broadcast: conflict-free
    float4 kx = kslo[k], ky = kshi[k];
    float4 vx = vslo[k], vy = vshi[k];
#pragma unroll
    for (int r = 0; r < 4; ++r) {
      float s = qa[r].x * kx.x + qa[r].y * kx.y + qa[r].z * kx.z +
                qa[r].w * kx.w + qb[r].x * ky.x + qb[r].y * ky.y +
                qb[r].z * ky.z + qb[r].w * ky.w;
      float p = exp2f(s);  // |orig score| <= 2.83: no max subtraction
      l[r] += p;
      a[r][0] = fmaf(p, vx.x, a[r][0]);
      a[r][1] = fmaf(p, vx.y, a[r][1]);
      a[r][2] = fmaf(p, vx.z, a[r][2]);
      a[r][3] = fmaf(p, vx.w, a[r][3]);
      a[r][4] = fmaf(p, vy.x, a[r][4]);
      a[r][5] = fmaf(p, vy.y, a[r][5]);
      a[r][6] = fmaf(p, vy.z, a[r][6]);
      a[r][7] = fmaf(p, vy.w, a[r][7]);
    }
  }
#pragma unroll
  for (int mm = 1; mm <= 4; mm <<= 1) {  // reduce over 8 k-parts: 3 steps
#pragma unroll
    for (int r = 0; r < 4; ++r) {
      l[r] += __shfl_xor(l[r], mm);
#pragma unroll
      for (int j = 0; j < 8; ++j) a[r][j] += __shfl_xor(a[r][j], mm);
    }
  }
  if (ko == 0) {
    float* aout = ws + 3 * (size_t)MATSZ;
#pragma unroll
    for (int r = 0; r < 4; ++r) {
      float inv = 1.f / l[r];
      float* d = aout + ((size_t)(b * 512 + srow0 + r)) * 128 + h * 8;
      ((float4*)d)[0] = make_float4(a[r][0] * inv, a[r][1] * inv,
                                    a[r][2] * inv, a[r][3] * inv);
      ((float4*)d)[1] = make_float4(a[r][4] * inv, a[r][5] * inv,
                                    a[r][6] * inv, a[r][7] * inv);
    }
  }
}

// ---------------- k_out v3: out = aout @ Wo^T, zero LDS ----------------------
// 4-row tiles, grid 512, 128 threads. Thread = col e, full Wo row in VGPRs,
// aout rows via wave-uniform loads (scalarized). No barriers.
__global__ __launch_bounds__(128) void k_out(
    const float* __restrict__ ws, const float* __restrict__ Wo,
    float* __restrict__ out) {
  const int e = threadIdx.x;
  const int tile = blockIdx.x;  // 0..511 (4 rows)
  float4 w[32];
  {
    const float4* wr = (const float4*)Wo + (size_t)e * 32;
#pragma unroll
    for (int i = 0; i < 32; ++i) w[i] = wr[i];
  }
  const float* aout = ws + 3 * (size_t)MATSZ + (size_t)tile * 512;
#pragma unroll
  for (int r = 0; r < 4; ++r) {
    const float4* ar = (const float4*)(aout + r * 128);  // uniform address
    float a = 0.f;
#pragma unroll
    for (int i = 0; i < 32; ++i) {
      float4 av = ar[i];  // wave-uniform -> scalar load
      a = fmaf(av.x, w[i].x, a);
      a = fmaf(av.y, w[i].y, a);
      a = fmaf(av.z, w[i].z, a);
      a = fmaf(av.w, w[i].w, a);
    }
    out[(size_t)(tile * 4 + r) * 128 + e] = a;
  }
}

extern "C" void kernel_launch(void* const* d_in, const int* in_sizes, int n_in,
                              void* d_out, int out_size, void* d_ws, size_t ws_size,
                              hipStream_t stream) {
  const float* x  = (const float*)d_in[0];
  const float* Wq = (const float*)d_in[1];
  const float* Wk = (const float*)d_in[2];
  const float* Wv = (const float*)d_in[3];
  const float* Wo = (const float*)d_in[4];
  const float* qp = (const float*)d_in[5];
  float* out = (float*)d_out;
  float* ws = (float*)d_ws;

  hipLaunchKernelGGL(k_qkvq, dim3(256, 3), dim3(128), 0, stream,
                     x, Wq, Wk, Wv, qp, ws);
  hipLaunchKernelGGL(k_attn, dim3(4, 64), dim3(256), 0, stream, ws);
  hipLaunchKernelGGL(k_out, dim3(512), dim3(128), 0, stream, ws, Wo, out);
}

// Round 12
// 42.751 us; speedup vs baseline: 1.7108x; 1.0916x over previous
//
#include <hip/hip_runtime.h>
#include <cmath>

#define MATSZ 262144                 // 2048 * 128
#define QKV_OFF 0                    // qkv[3][64][512][8]
#define AOUT_OFF (3 * MATSZ)         // aout[2048][128]

// ---------------- k_qkvq: QKV projection + quantum closed form ---------------
// thread = (col e, K-half); W row fragment in regs (issued BEFORE staging
// barrier so L2 latency hides under it); x rows broadcast from LDS; K-halves
// combined via LDS partials. grid (256,3) = 768 blocks = 3/CU.  [R7 proven]
__global__ __launch_bounds__(256, 3) void k_qkvq(
    const float* __restrict__ x, const float* __restrict__ Wq,
    const float* __restrict__ Wk, const float* __restrict__ Wv,
    const float* __restrict__ qp, float* __restrict__ ws) {
  __shared__ float xs[8][128];     // 4 KB
  __shared__ float th[2][8][128];  // 8 KB partial sums per K-half
  const int t = threadIdx.x;
  const int tile = blockIdx.x;  // 0..255 (8 rows each)
  const int m = blockIdx.y;     // 0..2
  const float* W = (m == 0) ? Wq : (m == 1) ? Wk : Wv;
  const int e = t & 127, half = t >> 7;
  float4 w[16];
  {
    const float4* wr = (const float4*)W + (size_t)e * 32 + half * 16;
#pragma unroll
    for (int i = 0; i < 16; ++i) w[i] = wr[i];
  }
  ((float4*)&xs[0][0])[t] = ((const float4*)(x + (size_t)tile * 1024))[t];
  __syncthreads();
  const float4* xs4 = (const float4*)&xs[0][0];
#pragma unroll
  for (int r = 0; r < 8; ++r) {
    float a = 0.f;
    const float4* xr = xs4 + r * 32 + half * 16;
#pragma unroll
    for (int i = 0; i < 16; ++i) {
      float4 xv = xr[i];  // LDS broadcast (wave-uniform addr)
      a = fmaf(xv.x, w[i].x, a);
      a = fmaf(xv.y, w[i].y, a);
      a = fmaf(xv.z, w[i].z, a);
      a = fmaf(xv.w, w[i].w, a);
    }
    th[half][r][e] = a;  // lanes e-consecutive: conflict-free
  }
  __syncthreads();
  // quantum tail: thread = (row rg, half-head cg); cols 4cg..4cg+3.
  const int cg = t & 31, rg = t >> 5;
  const float4* th4 = (const float4*)&th[0][0][0];
  float4 s0 = th4[rg * 32 + cg];
  float4 s1 = th4[256 + rg * 32 + cg];
  float4 a4 = make_float4(s0.x + s1.x, s0.y + s1.y, s0.z + s1.z, s0.w + s1.w);
  const int j0 = (cg & 1) * 4;
  float4 qs;
  qs.x = qp[j0 + 0] + qp[8 + j0 + 0];
  qs.y = qp[j0 + 1] + qp[8 + j0 + 1];
  qs.z = qp[j0 + 2] + qp[8 + j0 + 2];
  qs.w = qp[j0 + 3] + qp[8 + j0 + 3];
  float4 c;
  c.x = __cosf(a4.x + qs.x);
  c.y = __cosf(a4.y + qs.y);
  c.z = __cosf(a4.z + qs.z);
  c.w = __cosf(a4.w + qs.w);
  float4 u;  // local prefix: (c0, c1, c0c2, c1c3) in this half's numbering
  u.x = c.x; u.y = c.y; u.z = c.x * c.z; u.w = c.y * c.w;
  float gz = __shfl_xor(u.z, 1);  // even lane's (c0*c2) -> odd lane
  float gw = __shfl_xor(u.w, 1);  // even lane's (c1*c3) -> odd lane
  const bool hi = (cg & 1) != 0;
  float mz = hi ? gz : 1.f, mw = hi ? gw : 1.f;
  float4 o;
  o.x = u.x * mz; o.y = u.y * mw; o.z = u.z * mz; o.w = u.w * mw;
  const int h = cg >> 1;
  int row = tile * 8 + rg;
  int b = row >> 9, s = row & 511;
  float* dst = ws + QKV_OFF + (size_t)m * MATSZ +
               ((size_t)((b << 4) + h) * 512 + s) * 8 + (hi ? 4 : 0);
  *(float4*)dst = o;
}

// ---------------- k_attn: attention per (bh, 64-row q-tile) ------------------
// grid (8,64) = 512 blocks = 2 blk/CU (8 waves/CU). 256 thr = 16 qslots
// (4 rows each) x 16 k-parts. 4 rows/thread halves LDS-read instrs vs R=2.
// Access k=i*16+ko: 16 distinct consecutive f4 addrs x 4-lane broadcast per
// wave = conflict-free. Reduce: 4 DPP-able shuffle steps.
__global__ __launch_bounds__(256, 2) void k_attn(float* __restrict__ ws) {
  __shared__ float4 kslo[512], kshi[512], vslo[512], vshi[512];  // 32 KB
  const int qt = blockIdx.x;  // 0..7
  const int bh = blockIdx.y;  // 0..63
  const float* qkv = ws + QKV_OFF;
  const float* Qg = qkv + (size_t)bh * 4096;
  const float4* Kg = (const float4*)(qkv + MATSZ + (size_t)bh * 4096);
  const float4* Vg = (const float4*)(qkv + 2 * (size_t)MATSZ + (size_t)bh * 4096);
  const int t = threadIdx.x;
  for (int k = t; k < 512; k += 256) {
    kslo[k] = Kg[2 * k]; kshi[k] = Kg[2 * k + 1];
    vslo[k] = Vg[2 * k]; vshi[k] = Vg[2 * k + 1];
  }
  const int qslot = t >> 4, ko = t & 15;
  const int row0 = qt * 64 + qslot * 4;
  const float scale = 0.51013389376f;  // log2(e)/sqrt(8)
  float4 qa[4], qb[4];
#pragma unroll
  for (int r = 0; r < 4; ++r) {
    qa[r] = ((const float4*)(Qg + (size_t)(row0 + r) * 8))[0];
    qb[r] = ((const float4*)(Qg + (size_t)(row0 + r) * 8))[1];
    qa[r].x *= scale; qa[r].y *= scale; qa[r].z *= scale; qa[r].w *= scale;
    qb[r].x *= scale; qb[r].y *= scale; qb[r].z *= scale; qb[r].w *= scale;
  }
  __syncthreads();
  float l[4] = {0.f, 0.f, 0.f, 0.f};
  float a[4][8];
#pragma unroll
  for (int r = 0; r < 4; ++r)
#pragma unroll
    for (int j = 0; j < 8; ++j) a[r][j] = 0.f;
#pragma unroll 2
  for (int i = 0; i < 32; ++i) {
    int k = i * 16 + ko;
    float4 kx = kslo[k], ky = kshi[k];
    float4 vx = vslo[k], vy = vshi[k];
#pragma unroll
    for (int r = 0; r < 4; ++r) {
      float s = qa[r].x * kx.x + qa[r].y * kx.y + qa[r].z * kx.z +
                qa[r].w * kx.w + qb[r].x * ky.x + qb[r].y * ky.y +
                qb[r].z * ky.z + qb[r].w * ky.w;
      float p = exp2f(s);  // |orig score| <= 2.83: no max subtraction
      l[r] += p;
      a[r][0] = fmaf(p, vx.x, a[r][0]);
      a[r][1] = fmaf(p, vx.y, a[r][1]);
      a[r][2] = fmaf(p, vx.z, a[r][2]);
      a[r][3] = fmaf(p, vx.w, a[r][3]);
      a[r][4] = fmaf(p, vy.x, a[r][4]);
      a[r][5] = fmaf(p, vy.y, a[r][5]);
      a[r][6] = fmaf(p, vy.z, a[r][6]);
      a[r][7] = fmaf(p, vy.w, a[r][7]);
    }
  }
#pragma unroll
  for (int mm = 1; mm <= 8; mm <<= 1) {  // 4 steps, all within 16 lanes (DPP)
#pragma unroll
    for (int r = 0; r < 4; ++r) {
      l[r] += __shfl_xor(l[r], mm);
#pragma unroll
      for (int j = 0; j < 8; ++j) a[r][j] += __shfl_xor(a[r][j], mm);
    }
  }
  if (ko == 0) {
    int b = bh >> 4, h = bh & 15;
    float* aout = ws + AOUT_OFF;
#pragma unroll
    for (int r = 0; r < 4; ++r) {
      float inv = 1.f / l[r];
      float* d = aout + ((size_t)(b * 512 + row0 + r)) * 128 + h * 8;
      ((float4*)d)[0] = make_float4(a[r][0] * inv, a[r][1] * inv,
                                    a[r][2] * inv, a[r][3] * inv);
      ((float4*)d)[1] = make_float4(a[r][4] * inv, a[r][5] * inv,
                                    a[r][6] * inv, a[r][7] * inv);
    }
  }
}

// ---------------- k_out: out = aout @ Wo^T -----------------------------------
// 4-row tiles, grid 512 = 2/CU. W fragment prefetch before staging barrier.
// [R7 proven]
__global__ __launch_bounds__(256, 2) void k_out(
    const float* __restrict__ ws, const float* __restrict__ Wo,
    float* __restrict__ out) {
  __shared__ float as_[4][128];    // 2 KB
  __shared__ float th[2][4][128];  // 4 KB
  const int t = threadIdx.x;
  const int tile = blockIdx.x;  // 0..511
  const float* aout = ws + AOUT_OFF;
  const int e = t & 127, half = t >> 7;
  float4 w[16];
  {
    const float4* wr = (const float4*)Wo + (size_t)e * 32 + half * 16;
#pragma unroll
    for (int i = 0; i < 16; ++i) w[i] = wr[i];  // in flight during staging
  }
  if (t < 128)
    ((float4*)&as_[0][0])[t] = ((const float4*)(aout + (size_t)tile * 512))[t];
  __syncthreads();
  const float4* as4 = (const float4*)&as_[0][0];
#pragma unroll
  for (int r = 0; r < 4; ++r) {
    float a = 0.f;
    const float4* ar = as4 + r * 32 + half * 16;
#pragma unroll
    for (int i = 0; i < 16; ++i) {
      float4 av = ar[i];  // LDS broadcast
      a = fmaf(av.x, w[i].x, a);
      a = fmaf(av.y, w[i].y, a);
      a = fmaf(av.z, w[i].z, a);
      a = fmaf(av.w, w[i].w, a);
    }
    th[half][r][e] = a;
  }
  __syncthreads();
  if (t < 128) {
    const int cg = t & 31, rg = t >> 5;
    const float4* th4 = (const float4*)&th[0][0][0];
    float4 p0 = th4[rg * 32 + cg];
    float4 p1 = th4[128 + rg * 32 + cg];
    float4 o = make_float4(p0.x + p1.x, p0.y + p1.y, p0.z + p1.z, p0.w + p1.w);
    ((float4*)(out + (size_t)(tile * 4 + rg) * 128))[cg] = o;
  }
}

extern "C" void kernel_launch(void* const* d_in, const int* in_sizes, int n_in,
                              void* d_out, int out_size, void* d_ws, size_t ws_size,
                              hipStream_t stream) {
  const float* x  = (const float*)d_in[0];
  const float* Wq = (const float*)d_in[1];
  const float* Wk = (const float*)d_in[2];
  const float* Wv = (const float*)d_in[3];
  const float* Wo = (const float*)d_in[4];
  const float* qp = (const float*)d_in[5];
  float* out = (float*)d_out;
  float* ws = (float*)d_ws;

  hipLaunchKernelGGL(k_qkvq, dim3(256, 3), dim3(256), 0, stream,
                     x, Wq, Wk, Wv, qp, ws);
  hipLaunchKernelGGL(k_attn, dim3(8, 64), dim3(256), 0, stream, ws);
  hipLaunchKernelGGL(k_out, dim3(512), dim3(256), 0, stream, ws, Wo, out);
}